// Round 16
// baseline (2804.813 us; speedup 1.0000x reference)
//
#include <hip/hip_runtime.h>
#include <hip/hip_bf16.h>
#include <stdint.h>

#define BATCH 64
#define SEQ   512
#define HID   1024
#define VOC   4096
#define LROWS (SEQ*BATCH)   // 32768 output rows
#define HN    (BATCH*HID)
#define NGRP  8             // independent batch-row groups (8 rows each)
#define RPG   8
#define NWK   32            // worker wgs per group (32 cols each)
#define CPW   32
#define NWGT  (NGRP*NWK)    // 256 wgs

// ctrl layout (u32 word indices)
#define BAR_CNT 0                         // init barrier counter
#define FFLG    512                       // fast flags [SEQ][NGRP][64] (plain)
#define SFLG    (FFLG + SEQ*NGRP*64)      // slow flags [SEQ][NGRP][64] (atomic)
#define CTRL_WORDS (SFLG + SEQ*NGRP*64)

typedef __attribute__((ext_vector_type(4))) float f32x4;
typedef __attribute__((ext_vector_type(8))) short short8;

__device__ __forceinline__ unsigned short f2bf(float f) {
    unsigned int u = __builtin_bit_cast(unsigned int, f);
    u += 0x7fffu + ((u >> 16) & 1u);   // round-to-nearest-even
    return (unsigned short)(u >> 16);
}

__device__ __forceinline__ float tanh_fast(float x) {
    float e = __expf(2.f * x);
    return (e - 1.f) * __frcp_rn(e + 1.f);
}

// sc0sc1 write-through store: at LLC (device-visible) once vmcnt retires (proven r4+)
__device__ __forceinline__ void st_bf16_llc(unsigned short* p, unsigned short v) {
    unsigned vv = v;
    asm volatile("global_store_short %0, %1, off sc0 sc1" :: "v"(p), "v"(vv) : "memory");
}
// plain flag store (lands in producer's L2; cheap; backup atomic guarantees delivery)
__device__ __forceinline__ void st_flag_fast(unsigned* p, unsigned v) {
    asm volatile("global_store_dword %0, %1, off" :: "v"(p), "v"(v) : "memory");
}
// sc0 poll: bypass L1, read own/shared L2 -- NO fabric traffic when line is local
__device__ __forceinline__ unsigned ld_flag_fast(const unsigned* p) {
    unsigned v;
    asm volatile("global_load_dword %0, %1, off sc0\ns_waitcnt vmcnt(0)"
                 : "=v"(v) : "v"(p) : "memory");
    return v;
}

// async global->LDS, 16B per lane (gemm only)
#define GLL16(g, l) __builtin_amdgcn_global_load_lds( \
    (const __attribute__((address_space(1))) void*)(g), \
    (__attribute__((address_space(3))) void*)(l), 16, 0, 0)

// flat counter-poll init barrier (proven r4/r10 mechanics)
__device__ __forceinline__ void gbar_flat(unsigned* cnt, unsigned target, int tid) {
    asm volatile("s_waitcnt vmcnt(0)" ::: "memory");
    __syncthreads();
    if (tid == 0) {
        __hip_atomic_fetch_add(cnt, 1u, __ATOMIC_RELAXED, __HIP_MEMORY_SCOPE_AGENT);
        unsigned c; long it = 0;
        do {
            __builtin_amdgcn_s_sleep(1);
            c = __hip_atomic_load(cnt, __ATOMIC_RELAXED, __HIP_MEMORY_SCOPE_AGENT);
        } while (c < target && ++it < (1L << 24));   // fail visibly, never hang
    }
    __syncthreads();
    asm volatile("" ::: "memory");
}

// ---------------------------------------------------------------------------
// Generic: in[R][C] f32  ->  out[C][R] bf16   (transpose + convert)
// ---------------------------------------------------------------------------
__global__ __launch_bounds__(256) void k_transpose_f32_bf16(
    const float* __restrict__ in, unsigned short* __restrict__ out, int R, int C)
{
    __shared__ float tile[64][65];
    const int tid = threadIdx.x;
    const int c0 = blockIdx.x * 64;
    const int r0 = blockIdx.y * 64;
    #pragma unroll
    for (int i = 0; i < 16; ++i) {
        int idx = tid + i*256;
        int r = idx >> 6, c = idx & 63;
        tile[r][c] = in[(size_t)(r0 + r)*C + c0 + c];
    }
    __syncthreads();
    #pragma unroll
    for (int i = 0; i < 16; ++i) {
        int idx = tid + i*256;
        int r = idx >> 6, c = idx & 63;
        out[(size_t)(c0 + r)*R + r0 + c] = f2bf(tile[c][r]);
    }
}

// ---------------------------------------------------------------------------
// Persistent recurrence: 256 wgs x 128 thr (2 waves), cooperative.
// CHAMPION RESTORE (r10 protocol, measured best of 7 variants: 4.4 us/step):
//   static (g = wg>>5, slot = wg&31); wave w owns cols [slot*32+16w, +16)
//   of batch rows [8g, 8g+8); W_hh^T slice XOR-swizzled in 64 KB LDS.
// Data: sc0sc1 write-through + vmcnt(0) drain BEFORE flags (proven r4-r15).
// Flags: DUAL -- plain fast store (producer L2) + relaxed-atomic slow store
//   (LLC). Consumer: sc0 poll every iteration (local-L2, zero fabric
//   traffic) + relaxed-atomic backup every 4th (sole correctness carrier).
//   r14/r15 showed every-iteration LLC polls regress (-8%, 3x FETCH).
// Staleness: write-once-read-once ring + start-of-kernel acquire fence;
//   replays recompute bit-identical values (r10-r12: 3x replay-validated).
// ---------------------------------------------------------------------------
__global__ __launch_bounds__(128, 1) void k_rnn_persist(
    const unsigned short* __restrict__ WhhT, // [1024 c][1024 k] bf16
    const float* __restrict__ bh,
    const float* __restrict__ Wxh,           // [4096][1024] f32
    const int*   __restrict__ X,             // [64][512]
    const float* __restrict__ H0,            // [64][1024] f32
    unsigned short* __restrict__ H0s,        // [64][1024] bf16 staging
    unsigned short* __restrict__ Agem,       // [512*64][1024] bf16 (gemm A)
    float* __restrict__ Hfin,
    unsigned* __restrict__ ctrl)             // zeroed per call
{
    __shared__ unsigned short Wl[CPW*HID];   // 64 KB, [c][k] XOR-swizzled
    const int tid  = threadIdx.x;
    const int lane = tid & 63;
    const int wave = tid >> 6;
    const int wg   = blockIdx.x;
    const int g    = wg >> 5;
    const int slot = wg & 31;

    // one-time cache invalidate: clears stale lines from prior replays
    __builtin_amdgcn_fence(__ATOMIC_ACQUIRE, "agent");

    // ---- stage W_hh^T col-slice into LDS (swizzle: byte ^= (c&7)<<4) ----
    #pragma unroll
    for (int it = 0; it < 32; ++it) {
        int sl = it*128 + tid;               // 0..4095 16B chunks
        int cc = sl >> 7;                    // 0..31
        int k0 = (sl & 127) * 8;
        short8 v = *(const short8*)&WhhT[(size_t)(slot*CPW + cc)*HID + k0];
        int byte = cc*2048 + k0*2;
        byte ^= (cc & 7) << 4;
        *(short8*)((char*)Wl + byte) = v;
    }
    // ---- stage my H0 slice (bf16) at LLC ----
    for (int i = tid; i < RPG*CPW; i += 128) {
        int r = i >> 5, cc = i & 31;
        int b = g*RPG + r, gc = slot*CPW + cc;
        st_bf16_llc(&H0s[b*HID + gc], f2bf(H0[b*HID + gc]));
    }
    gbar_flat(ctrl + BAR_CNT, NWGT, tid);    // H0s + Wl ready everywhere

    const int col   = slot*CPW + wave*16 + (lane & 15);
    const float bhc = bh[col];
    const int c     = wave*16 + (lane & 15);     // Wl row
    const int rq    = (lane >> 4) & 1;           // row-quad (dup for lanes>=32)

    float xv[4];
    #pragma unroll
    for (int q = 0; q < 4; ++q)
        xv[q] = Wxh[(size_t)X[(g*RPG + rq*4 + q)*SEQ + 0]*HID + col];

    for (int t = 0; t < SEQ; ++t) {
        if (t > 0) {   // wait for my group's 64 producer-wave flags of step t
            const size_t fi = ((size_t)t*NGRP + g)*64 + lane;
            const unsigned* ff = ctrl + FFLG + fi;
            const unsigned* sf = ctrl + SFLG + fi;
            unsigned v = 0; int it = 0;
            while (true) {
                if (v == 0u) v = ld_flag_fast(ff);          // local-L2 poll
                if (__ballot(v == 0u) == 0ull) break;
                if (v == 0u && (it & 3) == 3)               // LLC reality-check
                    v = __hip_atomic_load(sf, __ATOMIC_RELAXED,
                                          __HIP_MEMORY_SCOPE_AGENT);
                if (__ballot(v == 0u) == 0ull) break;
                if (it > 64) __builtin_amdgcn_s_sleep(1);
                if (++it > (1 << 20)) break;   // visible failure, never a hang
            }
        }

        const unsigned short* src = (t == 0) ? H0s
                                             : Agem + (size_t)(t - 1)*HN;
        const unsigned short* arow =
            src + (size_t)(g*RPG + (lane & 7))*HID + (lane >> 4)*8;
        short8 af[32];
        #pragma unroll
        for (int ks = 0; ks < 32; ++ks)
            af[ks] = *(const short8*)(arow + ks*32);

        float xvn[4] = {0.f, 0.f, 0.f, 0.f};
        if (t + 1 < SEQ) {
            #pragma unroll
            for (int q = 0; q < 4; ++q)
                xvn[q] = Wxh[(size_t)X[(g*RPG + rq*4 + q)*SEQ + (t + 1)]*HID + col];
        }

        f32x4 acc0 = (f32x4){0.f,0.f,0.f,0.f};
        f32x4 acc1 = (f32x4){0.f,0.f,0.f,0.f};
        #pragma unroll
        for (int ks = 0; ks < 32; ks += 2) {
            int byte0 = c*2048 + ks*64 + (lane >> 4)*16;
            int byte1 = byte0 + 64;
            byte0 ^= (lane & 7) << 4;
            byte1 ^= (lane & 7) << 4;
            short8 b0 = *(const short8*)((const char*)Wl + byte0);
            short8 b1 = *(const short8*)((const char*)Wl + byte1);
            acc0 = __builtin_amdgcn_mfma_f32_16x16x32_bf16(af[ks],   b0, acc0, 0,0,0);
            acc1 = __builtin_amdgcn_mfma_f32_16x16x32_bf16(af[ks+1], b1, acc1, 0,0,0);
        }
        f32x4 acc = acc0 + acc1;

        unsigned short* orow = Agem + (size_t)t*HN;
        if ((lane >> 4) < 2) {    // rows 0..7 real, rest are pad duplicates
            #pragma unroll
            for (int q = 0; q < 4; ++q) {
                int b = g*RPG + (lane >> 4)*4 + q;
                float h = tanh_fast(acc[q] + xv[q] + bhc);
                st_bf16_llc(&orow[(size_t)b*HID + col], f2bf(h));
                if (t == SEQ - 1) Hfin[b*HID + col] = h;
            }
        }
        #pragma unroll
        for (int q = 0; q < 4; ++q) xv[q] = xvn[q];

        // ---- publish: drain data to LLC, then BOTH flags ----
        if (t + 1 < SEQ) {
            asm volatile("s_waitcnt vmcnt(0)" ::: "memory");
            if (lane == 0) {
                size_t fi = ((size_t)(t + 1)*NGRP + g)*64 + slot*2 + wave;
                st_flag_fast(ctrl + FFLG + fi, 1u);
                __hip_atomic_store(ctrl + SFLG + fi, 1u,
                                   __ATOMIC_RELAXED, __HIP_MEMORY_SCOPE_AGENT);
            }
        }
        // t == SEQ-1: end-of-dispatch release publishes Agem[511]/Hfin
    }
}

// ---------------------------------------------------------------------------
// Logits GEMM: C[L][4096] = A[L][1024](bf16) * Bt[4096][1024]^T(bf16) + b_q
// 128x128 tile, BK=64, 4 waves (2x2); XCD-aware block swizzle. (Proven.)
// ---------------------------------------------------------------------------
__global__ __launch_bounds__(256) void k_gemm_logits(
    const unsigned short* __restrict__ A,
    const unsigned short* __restrict__ Bt,
    const float* __restrict__ bq,
    float* __restrict__ C)
{
    __shared__ unsigned short lA[128*64];
    __shared__ unsigned short lB[128*64];
    const int tid  = threadIdx.x;
    const int lane = tid & 63;
    const int wave = tid >> 6;
    const int wm = wave >> 1, wn = wave & 1;

    const int NBM = LROWS/128, NBN = VOC/128;          // 256 x 32 = 8192
    int lid = blockIdx.y * NBM + blockIdx.x;
    int swz = (lid & 7) * (NBM*NBN/8) + (lid >> 3);
    const int bm = swz % NBM;
    const int bn = swz / NBM;
    const int rowA0 = bm * 128;
    const int rowB0 = bn * 128;

    f32x4 acc[4][4];
    #pragma unroll
    for (int i = 0; i < 4; ++i)
        #pragma unroll
        for (int j = 0; j < 4; ++j)
            acc[i][j] = (f32x4){0.f, 0.f, 0.f, 0.f};

    for (int kt = 0; kt < HID; kt += 64) {
        __syncthreads();
        #pragma unroll
        for (int i = 0; i < 4; ++i) {
            int slot = i*256 + tid;
            int row  = slot >> 3;
            int colb = (slot & 7) * 8;
            const unsigned short* ga = A  + (size_t)(rowA0 + row)*HID + kt + colb;
            const unsigned short* gb = Bt + (size_t)(rowB0 + row)*HID + kt + colb;
            unsigned short* la = lA + (i*256 + (tid >> 6)*64)*8;
            unsigned short* lb = lB + (i*256 + (tid >> 6)*64)*8;
            GLL16(ga, la);
            GLL16(gb, lb);
        }
        __syncthreads();
        #pragma unroll
        for (int ks = 0; ks < 2; ++ks) {
            short8 af[4], bf[4];
            #pragma unroll
            for (int i = 0; i < 4; ++i) {
                int row = wm*64 + i*16 + (lane & 15);
                int k   = ks*32 + (lane >> 4)*8;
                af[i] = *(const short8*)&lA[row*64 + k];
            }
            #pragma unroll
            for (int j = 0; j < 4; ++j) {
                int row = wn*64 + j*16 + (lane & 15);
                int k   = ks*32 + (lane >> 4)*8;
                bf[j] = *(const short8*)&lB[row*64 + k];
            }
            #pragma unroll
            for (int i = 0; i < 4; ++i)
                #pragma unroll
                for (int j = 0; j < 4; ++j)
                    acc[i][j] = __builtin_amdgcn_mfma_f32_16x16x32_bf16(af[i], bf[j], acc[i][j], 0, 0, 0);
        }
    }

    #pragma unroll
    for (int i = 0; i < 4; ++i) {
        int rbase = rowA0 + wm*64 + i*16 + (lane >> 4)*4;
        #pragma unroll
        for (int j = 0; j < 4; ++j) {
            int cc = rowB0 + wn*64 + j*16 + (lane & 15);
            float bqv = bq[cc];
            #pragma unroll
            for (int reg = 0; reg < 4; ++reg)
                C[(size_t)(rbase + reg)*VOC + cc] = acc[i][j][reg] + bqv;
        }
    }
}

// ---------------------------------------------------------------------------
extern "C" void kernel_launch(void* const* d_in, const int* in_sizes, int n_in,
                              void* d_out, int out_size, void* d_ws, size_t ws_size,
                              hipStream_t stream) {
    const int*   X   = (const int*)d_in[0];
    const float* H0  = (const float*)d_in[1];
    const float* Wxh = (const float*)d_in[2];
    const float* Whh = (const float*)d_in[3];
    const float* bh  = (const float*)d_in[4];
    const float* Whq = (const float*)d_in[5];
    const float* bq  = (const float*)d_in[6];
    float* out = (float*)d_out;

    // workspace layout (same offsets as proven r10)
    char* ws = (char*)d_ws;
    unsigned* ctrl = (unsigned*)ws;                                       // ~1.1 MB
    unsigned short* WhhT = (unsigned short*)(ws + (size_t)4*1024*1024);   // 2 MB
    unsigned short* BtHq = (unsigned short*)(ws + (size_t)8*1024*1024);   // 8 MB
    unsigned short* H0s  = (unsigned short*)(ws + (size_t)16*1024*1024);  // 128 KB
    unsigned short* Agem = (unsigned short*)(ws + (size_t)20*1024*1024);  // 64 MB

    hipMemsetAsync(ctrl, 0, (size_t)CTRL_WORDS * sizeof(unsigned), stream);

    k_transpose_f32_bf16<<<dim3(HID/64, HID/64), 256, 0, stream>>>(Whh, WhhT, HID, HID);
    k_transpose_f32_bf16<<<dim3(VOC/64, HID/64), 256, 0, stream>>>(Whq, BtHq, HID, VOC);

    float* Hfin = out + (size_t)LROWS * VOC;
    {
        const unsigned short* a0 = WhhT;
        const float* a1 = bh;
        const float* a2 = Wxh;
        const int*   a3 = X;
        const float* a4 = H0;
        unsigned short* a5 = H0s;
        unsigned short* a6 = Agem;
        float* a7 = Hfin;
        unsigned* a8 = ctrl;
        void* args[] = { &a0, &a1, &a2, &a3, &a4, &a5, &a6, &a7, &a8 };
        hipLaunchCooperativeKernel((void*)k_rnn_persist, dim3(NWGT), dim3(128),
                                   args, 0, stream);
    }

    k_gemm_logits<<<dim3(LROWS/128, VOC/128), 256, 0, stream>>>(Agem, BtHq, bq, out);
}

// Round 17
// 2654.675 us; speedup vs baseline: 1.0566x; 1.0566x over previous
//
#include <hip/hip_runtime.h>
#include <hip/hip_bf16.h>
#include <stdint.h>

#define BATCH 64
#define SEQ   512
#define HID   1024
#define VOC   4096
#define LROWS (SEQ*BATCH)   // 32768 output rows
#define NGRP  8             // independent batch-row groups
#define RPG   8             // batch rows per group
#define NWK   32            // worker wgs per group (32 cols each)
#define CPW   32            // hidden cols per worker

// ctrl layout (u32 word indices)
#define CNT_BASE   0        // 8 claim counters, stride 32 words
#define BAR_CNT    256      // init barrier arrival counter
#define BAR_REL    288      // init barrier release flag
#define FFLG       512                  // fast flags [SEQ][NGRP][64]
#define SFLG       (512 + SEQ*NGRP*64)  // slow flags [SEQ][NGRP][64]
#define CTRL_WORDS (512 + 2*SEQ*NGRP*64)

typedef __attribute__((ext_vector_type(4))) float f32x4;
typedef __attribute__((ext_vector_type(8))) short short8;

__device__ __forceinline__ unsigned short f2bf(float f) {
    unsigned int u = __builtin_bit_cast(unsigned int, f);
    u += 0x7fffu + ((u >> 16) & 1u);   // round-to-nearest-even
    return (unsigned short)(u >> 16);
}

__device__ __forceinline__ float tanh_fast(float x) {
    float e = __expf(2.f * x);
    return (e - 1.f) * __frcp_rn(e + 1.f);
}

// sc0sc1 write-through store: visible device-wide once vmcnt retires (proven r4-r16)
__device__ __forceinline__ void st_bf16_llc(unsigned short* p, unsigned short v) {
    unsigned vv = v;
    asm volatile("global_store_short %0, %1, off sc0 sc1" :: "v"(p), "v"(vv) : "memory");
}
// fast flag: plain store (lands in producer's L2; same-XCD readers can see it)
__device__ __forceinline__ void st_flag_fast(unsigned* p, unsigned v) {
    asm volatile("global_store_dword %0, %1, off" :: "v"(p), "v"(v) : "memory");
}
// fast poll: sc0 load = bypass L1, read (shared) L2
__device__ __forceinline__ unsigned ld_flag_fast(const unsigned* p) {
    unsigned v;
    asm volatile("global_load_dword %0, %1, off sc0\ns_waitcnt vmcnt(0)"
                 : "=v"(v) : "v"(p) : "memory");
    return v;
}

// async global->LDS, 16B per lane (gemm only)
#define GLL16(g, l) __builtin_amdgcn_global_load_lds( \
    (const __attribute__((address_space(1))) void*)(g), \
    (__attribute__((address_space(3))) void*)(l), 16, 0, 0)

// ---------------------------------------------------------------------------
// Generic: in[R][C] f32  ->  out[C][R] bf16   (transpose + convert)
// ---------------------------------------------------------------------------
__global__ __launch_bounds__(256) void k_transpose_f32_bf16(
    const float* __restrict__ in, unsigned short* __restrict__ out, int R, int C)
{
    __shared__ float tile[64][65];
    const int tid = threadIdx.x;
    const int c0 = blockIdx.x * 64;
    const int r0 = blockIdx.y * 64;
    #pragma unroll
    for (int i = 0; i < 16; ++i) {
        int idx = tid + i*256;
        int r = idx >> 6, c = idx & 63;
        tile[r][c] = in[(size_t)(r0 + r)*C + c0 + c];
    }
    __syncthreads();
    #pragma unroll
    for (int i = 0; i < 16; ++i) {
        int idx = tid + i*256;
        int r = idx >> 6, c = idx & 63;
        out[(size_t)(c0 + r)*R + r0 + c] = f2bf(tile[c][r]);
    }
}

// ---------------------------------------------------------------------------
// EXACT round-10 champion (2260 us persist, 98 MB FETCH).
// The XCD-affinity claim is NOT dead code: it makes each group XCD-pure, so
// each XCD's L2 only fetches its own group's H rows (98 vs 315 MB measured
// r10 vs r16). Dual flags: plain fast store + relaxed-atomic slow store;
// consumer sc0-polls (local L2, no fabric traffic) with every-4th atomic
// reality-check (sole correctness carrier). Data: sc0sc1 write-through +
// vmcnt drain before flags. Correctness placement-independent throughout.
// ---------------------------------------------------------------------------
__global__ __launch_bounds__(128, 1) void k_rnn_persist(
    const unsigned short* __restrict__ WhhT, // [1024 c][1024 k] bf16
    const float* __restrict__ bh,
    const float* __restrict__ Wxh,           // [4096][1024] f32
    const int*   __restrict__ X,             // [64][512]
    const float* __restrict__ H0,            // [64][1024] f32
    unsigned short* __restrict__ H0s,        // [64][1024] bf16 staging
    unsigned short* __restrict__ Agem,       // [512*64][1024] bf16 (gemm A)
    float* __restrict__ Hfin,
    unsigned* __restrict__ ctrl)             // zeroed per call
{
    __shared__ unsigned short Wl[CPW*HID];   // 64 KB, [c][k] XOR-swizzled
    __shared__ int s_g, s_slot;
    const int tid  = threadIdx.x;
    const int lane = tid & 63;
    const int wave = tid >> 6;

    // one-time cache invalidate: clears any stale lines from prior replays
    __builtin_amdgcn_fence(__ATOMIC_ACQUIRE, "agent");

    unsigned xcd;
    asm volatile("s_getreg_b32 %0, hwreg(HW_REG_XCC_ID)" : "=s"(xcd));

    // ---- claim a (group, slot): own-XCD affinity first, cyclic fallback.
    // Affinity gives XCD-pure groups (locality); any placement is correct.
    if (tid == 0) {
        int gg = 0, ss = 0;
        for (int i = 0; i < NGRP; ++i) {
            int cand = (int)((xcd + i) & 7);
            unsigned s = atomicAdd(ctrl + CNT_BASE + cand*32, 1u);
            if (s < NWK) { gg = cand; ss = (int)s; break; }
        }
        s_g = gg; s_slot = ss;
    }
    __syncthreads();
    const int g = s_g, slot = s_slot;

    // ---- stage W_hh^T col-slice into LDS (swizzle: byte ^= (c&7)<<4) ----
    #pragma unroll
    for (int it = 0; it < 32; ++it) {
        int sl = it*128 + tid;               // 0..4095 16B chunks
        int cc = sl >> 7;                    // 0..31
        int k0 = (sl & 127) * 8;
        short8 v = *(const short8*)&WhhT[(size_t)(slot*CPW + cc)*HID + k0];
        int byte = cc*2048 + k0*2;
        byte ^= (cc & 7) << 4;
        *(short8*)((char*)Wl + byte) = v;
    }
    // ---- stage my H0 slice (bf16) at LLC ----
    for (int i = tid; i < RPG*CPW; i += 128) {
        int r = i >> 5, cc = i & 31;
        int b = g*RPG + r, gc = slot*CPW + cc;
        st_bf16_llc(&H0s[b*HID + gc], f2bf(H0[b*HID + gc]));
    }
    // ---- one-time flat init barrier over all 256 wgs (proven r4 scheme) ----
    asm volatile("s_waitcnt vmcnt(0)" ::: "memory");
    __syncthreads();
    if (tid == 0) {
        unsigned old = __hip_atomic_fetch_add(ctrl + BAR_CNT, 1u,
                                              __ATOMIC_RELAXED, __HIP_MEMORY_SCOPE_AGENT);
        if (old == NGRP*NWK - 1u) {
            __hip_atomic_store(ctrl + BAR_REL, 1u,
                               __ATOMIC_RELAXED, __HIP_MEMORY_SCOPE_AGENT);
        } else {
            unsigned r; long it = 0;
            do {
                __builtin_amdgcn_s_sleep(1);
                r = __hip_atomic_load(ctrl + BAR_REL,
                                      __ATOMIC_RELAXED, __HIP_MEMORY_SCOPE_AGENT);
            } while (r == 0u && ++it < (1L << 24));   // fail visibly, never hang
        }
    }
    __syncthreads();

    const int col   = slot*CPW + wave*16 + (lane & 15);
    const float bhc = bh[col];
    const int c     = wave*16 + (lane & 15);     // Wl row
    const int rq    = (lane >> 4) & 1;           // row-quad (dup for lanes>=32)

    float xv[4];
    #pragma unroll
    for (int q = 0; q < 4; ++q)
        xv[q] = Wxh[(size_t)X[(g*RPG + rq*4 + q)*SEQ + 0]*HID + col];

    for (int t = 0; t < SEQ; ++t) {
        // ---- wait for my group's 64 producer-wave flags of step t ----
        if (t > 0) {
            const size_t fi = ((size_t)t*NGRP + g)*64 + lane;
            const unsigned* ff = ctrl + FFLG + fi;
            const unsigned* sf = ctrl + SFLG + fi;
            unsigned v = 0; int it = 0;
            while (true) {
                if (v == 0u) v = ld_flag_fast(ff);
                if (__ballot(v == 0u) == 0ull) break;
                if (v == 0u && (it & 3) == 3)
                    v = __hip_atomic_load(sf, __ATOMIC_RELAXED,
                                          __HIP_MEMORY_SCOPE_AGENT);
                if (__ballot(v == 0u) == 0ull) break;
                if (it > 64) __builtin_amdgcn_s_sleep(1);
                if (++it > (1 << 20)) break;   // visible failure, no 600s hang
            }
        }

        const unsigned short* src = (t == 0) ? H0s
                                             : Agem + (size_t)(t - 1)*BATCH*HID;
        const unsigned short* arow =
            src + (size_t)(g*RPG + (lane & 7))*HID + (lane >> 4)*8;
        short8 af[32];
        #pragma unroll
        for (int ks = 0; ks < 32; ++ks)
            af[ks] = *(const short8*)(arow + ks*32);

        float xvn[4] = {0.f, 0.f, 0.f, 0.f};
        if (t + 1 < SEQ) {
            #pragma unroll
            for (int q = 0; q < 4; ++q)
                xvn[q] = Wxh[(size_t)X[(g*RPG + rq*4 + q)*SEQ + (t + 1)]*HID + col];
        }

        f32x4 acc0 = (f32x4){0.f,0.f,0.f,0.f};
        f32x4 acc1 = (f32x4){0.f,0.f,0.f,0.f};
        #pragma unroll
        for (int ks = 0; ks < 32; ks += 2) {
            int byte0 = c*2048 + ks*64 + (lane >> 4)*16;
            int byte1 = byte0 + 64;
            byte0 ^= (lane & 7) << 4;
            byte1 ^= (lane & 7) << 4;
            short8 b0 = *(const short8*)((const char*)Wl + byte0);
            short8 b1 = *(const short8*)((const char*)Wl + byte1);
            acc0 = __builtin_amdgcn_mfma_f32_16x16x32_bf16(af[ks],   b0, acc0, 0,0,0);
            acc1 = __builtin_amdgcn_mfma_f32_16x16x32_bf16(af[ks+1], b1, acc1, 0,0,0);
        }
        f32x4 acc = acc0 + acc1;

        unsigned short* orow = Agem + (size_t)t*BATCH*HID;
        if ((lane >> 4) < 2) {    // rows 0..7 real, rest are pad duplicates
            #pragma unroll
            for (int q = 0; q < 4; ++q) {
                int b = g*RPG + (lane >> 4)*4 + q;
                float h = tanh_fast(acc[q] + xv[q] + bhc);
                st_bf16_llc(&orow[(size_t)b*HID + col], f2bf(h));
                if (t == SEQ - 1) Hfin[b*HID + col] = h;
            }
        }
        #pragma unroll
        for (int q = 0; q < 4; ++q) xv[q] = xvn[q];

        // ---- publish: drain data to LLC, then set BOTH flags ----
        if (t + 1 < SEQ) {
            asm volatile("s_waitcnt vmcnt(0)" ::: "memory");
            if (lane == 0) {
                size_t fi = ((size_t)(t + 1)*NGRP + g)*64 + slot*2 + wave;
                st_flag_fast(ctrl + FFLG + fi, 1u);
                __hip_atomic_store(ctrl + SFLG + fi, 1u,
                                   __ATOMIC_RELAXED, __HIP_MEMORY_SCOPE_AGENT);
            }
        }
        // t == SEQ-1: stores drain at kernel end (stream order before gemm)
    }
}

// ---------------------------------------------------------------------------
// Logits GEMM: C[L][4096] = A[L][1024](bf16) * Bt[4096][1024]^T(bf16) + b_q
// 128x128 tile, BK=64, 4 waves (2x2); XCD-aware block swizzle
// ---------------------------------------------------------------------------
__global__ __launch_bounds__(256) void k_gemm_logits(
    const unsigned short* __restrict__ A,
    const unsigned short* __restrict__ Bt,
    const float* __restrict__ bq,
    float* __restrict__ C)
{
    __shared__ unsigned short lA[128*64];
    __shared__ unsigned short lB[128*64];
    const int tid  = threadIdx.x;
    const int lane = tid & 63;
    const int wave = tid >> 6;
    const int wm = wave >> 1, wn = wave & 1;

    const int NBM = LROWS/128, NBN = VOC/128;          // 256 x 32 = 8192
    int lid = blockIdx.y * NBM + blockIdx.x;
    int swz = (lid & 7) * (NBM*NBN/8) + (lid >> 3);
    const int bm = swz % NBM;
    const int bn = swz / NBM;
    const int rowA0 = bm * 128;
    const int rowB0 = bn * 128;

    f32x4 acc[4][4];
    #pragma unroll
    for (int i = 0; i < 4; ++i)
        #pragma unroll
        for (int j = 0; j < 4; ++j)
            acc[i][j] = (f32x4){0.f, 0.f, 0.f, 0.f};

    for (int kt = 0; kt < HID; kt += 64) {
        __syncthreads();
        #pragma unroll
        for (int i = 0; i < 4; ++i) {
            int slot = i*256 + tid;
            int row  = slot >> 3;
            int colb = (slot & 7) * 8;
            const unsigned short* ga = A  + (size_t)(rowA0 + row)*HID + kt + colb;
            const unsigned short* gb = Bt + (size_t)(rowB0 + row)*HID + kt + colb;
            unsigned short* la = lA + (i*256 + (tid >> 6)*64)*8;
            unsigned short* lb = lB + (i*256 + (tid >> 6)*64)*8;
            GLL16(ga, la);
            GLL16(gb, lb);
        }
        __syncthreads();
        #pragma unroll
        for (int ks = 0; ks < 2; ++ks) {
            short8 af[4], bf[4];
            #pragma unroll
            for (int i = 0; i < 4; ++i) {
                int row = wm*64 + i*16 + (lane & 15);
                int k   = ks*32 + (lane >> 4)*8;
                af[i] = *(const short8*)&lA[row*64 + k];
            }
            #pragma unroll
            for (int j = 0; j < 4; ++j) {
                int row = wn*64 + j*16 + (lane & 15);
                int k   = ks*32 + (lane >> 4)*8;
                bf[j] = *(const short8*)&lB[row*64 + k];
            }
            #pragma unroll
            for (int i = 0; i < 4; ++i)
                #pragma unroll
                for (int j = 0; j < 4; ++j)
                    acc[i][j] = __builtin_amdgcn_mfma_f32_16x16x32_bf16(af[i], bf[j], acc[i][j], 0, 0, 0);
        }
    }

    #pragma unroll
    for (int i = 0; i < 4; ++i) {
        int rbase = rowA0 + wm*64 + i*16 + (lane >> 4)*4;
        #pragma unroll
        for (int j = 0; j < 4; ++j) {
            int cc = rowB0 + wn*64 + j*16 + (lane & 15);
            float bqv = bq[cc];
            #pragma unroll
            for (int reg = 0; reg < 4; ++reg)
                C[(size_t)(rbase + reg)*VOC + cc] = acc[i][j][reg] + bqv;
        }
    }
}

// ---------------------------------------------------------------------------
extern "C" void kernel_launch(void* const* d_in, const int* in_sizes, int n_in,
                              void* d_out, int out_size, void* d_ws, size_t ws_size,
                              hipStream_t stream) {
    const int*   X   = (const int*)d_in[0];
    const float* H0  = (const float*)d_in[1];
    const float* Wxh = (const float*)d_in[2];
    const float* Whh = (const float*)d_in[3];
    const float* bh  = (const float*)d_in[4];
    const float* Whq = (const float*)d_in[5];
    const float* bq  = (const float*)d_in[6];
    float* out = (float*)d_out;

    // workspace layout (r10 offsets)
    char* ws = (char*)d_ws;
    unsigned* ctrl = (unsigned*)ws;                                       // ~2.1 MB
    unsigned short* WhhT = (unsigned short*)(ws + (size_t)4*1024*1024);   // 2 MB
    unsigned short* BtHq = (unsigned short*)(ws + (size_t)8*1024*1024);   // 8 MB
    unsigned short* H0s  = (unsigned short*)(ws + (size_t)16*1024*1024);  // 128 KB
    unsigned short* Agem = (unsigned short*)(ws + (size_t)20*1024*1024);  // 64 MB

    hipMemsetAsync(ctrl, 0, (size_t)CTRL_WORDS * sizeof(unsigned), stream);

    k_transpose_f32_bf16<<<dim3(HID/64, HID/64), 256, 0, stream>>>(Whh, WhhT, HID, HID);
    k_transpose_f32_bf16<<<dim3(VOC/64, HID/64), 256, 0, stream>>>(Whq, BtHq, HID, VOC);

    float* Hfin = out + (size_t)LROWS * VOC;
    {
        const unsigned short* a0 = WhhT;
        const float* a1 = bh;
        const float* a2 = Wxh;
        const int*   a3 = X;
        const float* a4 = H0;
        unsigned short* a5 = H0s;
        unsigned short* a6 = Agem;
        float* a7 = Hfin;
        unsigned* a8 = ctrl;
        void* args[] = { &a0, &a1, &a2, &a3, &a4, &a5, &a6, &a7, &a8 };
        hipLaunchCooperativeKernel((void*)k_rnn_persist, dim3(NGRP*NWK), dim3(128),
                                   args, 0, stream);
    }

    k_gemm_logits<<<dim3(LROWS/128, VOC/128), 256, 0, stream>>>(Agem, BtHq, bq, out);
}